// Round 4
// baseline (134.499 us; speedup 1.0000x reference)
//
#include <hip/hip_runtime.h>

// Problem constants (from reference)
#define NITEMS 100000
#define NRATE  5
#define BB     4096
#define LL     200
#define DD     64
#define NBUV   1563   // pre_uv blocks (1563*64 = 100032 >= NITEMS)

typedef short short8  __attribute__((ext_vector_type(8)));
typedef short short4v __attribute__((ext_vector_type(4)));
typedef float f32x4   __attribute__((ext_vector_type(4)));
typedef float f32x2   __attribute__((ext_vector_type(2)));
typedef int   i32x4   __attribute__((ext_vector_type(4)));
typedef int   i32x2   __attribute__((ext_vector_type(2)));

static __device__ __forceinline__ unsigned rtne16(float f) {
  // fp32 -> bf16 round-to-nearest-even, result in TOP 16 bits
  unsigned u = __builtin_bit_cast(unsigned, f);
  return u + 0x7fffu + ((u >> 16) & 1u);
}
// pack top halves of (a,b) -> {lo = a>>16, hi = b>>16} in one v_perm_b32
static __device__ __forceinline__ unsigned pk2bf(float a, float b) {
  return __builtin_amdgcn_perm(rtne16(b), rtne16(a), 0x07060302u);
}
static __device__ __forceinline__ short f2bf(float f) {
  return (short)(rtne16(f) >> 16);
}
// k-space permutation: storage position p holds h-component pi(p) = (p&3)*16 + (p>>2).
// Applied consistently to pre_uv, r5p, w2p rows -> all MFMA dots unchanged.
static __device__ __forceinline__ int kperm(int p) {
  return ((p & 3) << 4) | (p >> 2);
}

// ---------------------------------------------------------------------------
// k_pre: blocks 0..NBUV-1: pre_uv[item][p] = bf16(v2e[item] . w1a_row[pi(p)])
//        block NBUV      : w2p[o*64+p] = bf16(w2W[o][pi(p)]);
//                          r5p[r*64+p] = w1b[pi(p)] + r2e[r].w1b_row[pi(p)]
// 64 items/block (16 per wave), MFMA 16x16x32_bf16, kperm store = short4
// at offset n*4 (transpose-free, coalesced per quad).
// ---------------------------------------------------------------------------
__global__ __launch_bounds__(256) void k_pre(
    const float* __restrict__ v2e, const float* __restrict__ r2e,
    const float* __restrict__ w1W, const float* __restrict__ w1b,
    const float* __restrict__ w2W,
    short* __restrict__ pre_uv, short* __restrict__ w2p,
    float* __restrict__ r5p)
{
  const int tid = threadIdx.x;
  const int blk = blockIdx.x;

  if (blk >= NBUV) {
    for (int idx = tid; idx < 64 * 64; idx += 256) {
      const int o = idx >> 6, p = idx & 63;
      w2p[idx] = f2bf(w2W[o * 64 + kperm(p)]);
    }
    for (int idx = tid; idx < NRATE * 64; idx += 256) {
      const int r = idx >> 6, p = idx & 63;
      const int o = kperm(p);
      const float4* wr = reinterpret_cast<const float4*>(w1W + o * 128 + 64);
      const float4* rr = reinterpret_cast<const float4*>(r2e + r * 64);
      float s = w1b[o];
#pragma unroll
      for (int q = 0; q < 16; ++q) {
        const float4 a = wr[q], b = rr[q];
        s += a.x * b.x + a.y * b.y + a.z * b.z + a.w * b.w;
      }
      r5p[r * 64 + p] = s;
    }
    return;
  }

  const int wave = tid >> 6, lane = tid & 63;
  const int n = lane & 15, quad = lane >> 4;
  const int ibase = blk * 64 + wave * 16;

  // B fragment: B[k][o], k = kh*32 + quad*8 + j, o = nt*16 + n (fp32 -> bf16)
  short8 bfr[2][4];
#pragma unroll
  for (int nt = 0; nt < 4; ++nt)
#pragma unroll
    for (int kh = 0; kh < 2; ++kh) {
      const float4* p = reinterpret_cast<const float4*>(
          w1W + (nt * 16 + n) * 128 + kh * 32 + quad * 8);
      const float4 x0 = p[0], x1 = p[1];
      i32x4 pk = {(int)pk2bf(x0.x, x0.y), (int)pk2bf(x0.z, x0.w),
                  (int)pk2bf(x1.x, x1.y), (int)pk2bf(x1.z, x1.w)};
      bfr[kh][nt] = __builtin_bit_cast(short8, pk);
    }

  // A fragment: A[m=n][k=kh*32+quad*8+j]
  const int arow = min(ibase + n, NITEMS - 1);
  short8 afr[2];
#pragma unroll
  for (int kh = 0; kh < 2; ++kh) {
    const float4* p = reinterpret_cast<const float4*>(
        v2e + (size_t)arow * 64 + kh * 32 + quad * 8);
    const float4 x0 = p[0], x1 = p[1];
    i32x4 pk = {(int)pk2bf(x0.x, x0.y), (int)pk2bf(x0.z, x0.w),
                (int)pk2bf(x1.x, x1.y), (int)pk2bf(x1.z, x1.w)};
    afr[kh] = __builtin_bit_cast(short8, pk);
  }

  f32x4 d[4];
#pragma unroll
  for (int nt = 0; nt < 4; ++nt) {
    f32x4 z = {0.f, 0.f, 0.f, 0.f};
    z = __builtin_amdgcn_mfma_f32_16x16x32_bf16(afr[0], bfr[0][nt], z, 0, 0, 0);
    z = __builtin_amdgcn_mfma_f32_16x16x32_bf16(afr[1], bfr[1][nt], z, 0, 0, 0);
    d[nt] = z;
  }

  // C/D: lane (n,quad), reg (nt,r) = row quad*4+r, col nt*16+n.
  // kperm store: cols {nt*16+n} -> positions n*4+nt, one 8B store per r.
#pragma unroll
  for (int r = 0; r < 4; ++r) {
    const int item = ibase + quad * 4 + r;
    if (item < NITEMS) {
      i32x2 s = {(int)pk2bf(d[0][r], d[1][r]), (int)pk2bf(d[2][r], d[3][r])};
      *reinterpret_cast<i32x2*>(pre_uv + (size_t)item * 64 + n * 4) = s;
    }
  }
}

// ---------------------------------------------------------------------------
// k_main: one block per b. Waves each do 3 unmasked 16-row l-tiles
// (lbase = wave*16 + t*64, covers l<192); wave 0 additionally does the
// 8-row tail (l=192..199) with a 0/1 lane multiplier. All gathers issued
// before compute. h-construction in packed dword form.
// ---------------------------------------------------------------------------
__global__ __launch_bounds__(256) void k_main(
    const short* __restrict__ pre_uv, const float* __restrict__ r5p,
    const short* __restrict__ w2p, const float* __restrict__ w2b,
    const int* __restrict__ huv, const int* __restrict__ hrr,
    float* __restrict__ out)
{
  __shared__ __align__(16) float s_r5[5 * 68];   // stride 68 spreads row starts
  __shared__ float red[4][64];

  const int tid  = threadIdx.x;
  const int wave = tid >> 6, lane = tid & 63;
  const int n = lane & 15, quad = lane >> 4;
  const int b = blockIdx.x;

  for (int idx = tid; idx < 5 * 64; idx += 256)
    s_r5[(idx >> 6) * 68 + (idx & 63)] = r5p[idx];

  const int* hu = huv + b * LL;
  const int* hr = hrr + b * LL;
  int iv[4], ir[4];
#pragma unroll
  for (int t = 0; t < 3; ++t) {
    const int lc = wave * 16 + t * 64 + n;      // max 191 < 200: no clamp
    iv[t] = hu[lc];
    ir[t] = hr[lc];
  }
  const bool has_tail = (wave == 0);
  if (has_tail) {
    const int lc = min(192 + n, LL - 1);
    iv[3] = hu[lc];
    ir[3] = hr[lc];
  }

  // B fragments for W2 (permuted k-space): B[p][o] = w2p[o*64+p]
  short8 bfr[2][4];
#pragma unroll
  for (int nt = 0; nt < 4; ++nt)
#pragma unroll
    for (int kh = 0; kh < 2; ++kh)
      bfr[kh][nt] = *reinterpret_cast<const short8*>(
          w2p + (nt * 16 + n) * 64 + kh * 32 + quad * 8);

  f32x2 bias2[4];
#pragma unroll
  for (int nt = 0; nt < 4; ++nt) {
    const float bv = w2b[nt * 16 + n];
    bias2[nt] = f32x2{bv, bv};
  }

  // prefetch ALL pre_uv gathers (up to 8 independent 16B loads in flight)
  short8 u[4][2];
#pragma unroll
  for (int t = 0; t < 3; ++t)
#pragma unroll
    for (int kh = 0; kh < 2; ++kh)
      u[t][kh] = *reinterpret_cast<const short8*>(
          pre_uv + (size_t)iv[t] * 64 + kh * 32 + quad * 8);
  if (has_tail)
#pragma unroll
    for (int kh = 0; kh < 2; ++kh)
      u[3][kh] = *reinterpret_cast<const short8*>(
          pre_uv + (size_t)iv[3] * 64 + kh * 32 + quad * 8);

  __syncthreads();  // s_r5 ready

  f32x2 acc2[4] = {{0.f, 0.f}, {0.f, 0.f}, {0.f, 0.f}, {0.f, 0.f}};

#pragma unroll
  for (int t = 0; t < 3; ++t) {
    short8 afr[2];
#pragma unroll
    for (int kh = 0; kh < 2; ++kh) {
      const i32x4 up = __builtin_bit_cast(i32x4, u[t][kh]);
      const f32x2* rp = reinterpret_cast<const f32x2*>(
          s_r5 + ir[t] * 68 + kh * 32 + quad * 8);
      i32x4 hpk;
#pragma unroll
      for (int j = 0; j < 4; ++j) {
        const unsigned p = (unsigned)up[j];
        f32x2 uf = {__builtin_bit_cast(float, p << 16),
                    __builtin_bit_cast(float, p & 0xffff0000u)};
        f32x2 s = uf + rp[j];
        hpk[j] = (int)pk2bf(fmaxf(s.x, 0.f), fmaxf(s.y, 0.f));
      }
      afr[kh] = __builtin_bit_cast(short8, hpk);
    }

    f32x4 d[4];
#pragma unroll
    for (int nt = 0; nt < 4; ++nt) {
      f32x4 z = {0.f, 0.f, 0.f, 0.f};
      z = __builtin_amdgcn_mfma_f32_16x16x32_bf16(afr[0], bfr[0][nt], z, 0, 0, 0);
      z = __builtin_amdgcn_mfma_f32_16x16x32_bf16(afr[1], bfr[1][nt], z, 0, 0, 0);
      d[nt] = z;
    }

    // unmasked epilogue: acc += relu(d + bias), packed pairs
#pragma unroll
    for (int nt = 0; nt < 4; ++nt) {
      f32x2 p0 = f32x2{d[nt][0], d[nt][1]} + bias2[nt];
      f32x2 p1 = f32x2{d[nt][2], d[nt][3]} + bias2[nt];
      p0.x = fmaxf(p0.x, 0.f); p0.y = fmaxf(p0.y, 0.f);
      p1.x = fmaxf(p1.x, 0.f); p1.y = fmaxf(p1.y, 0.f);
      acc2[nt] += p0 + p1;
    }
  }

  if (has_tail) {
    const float m = (quad < 2) ? 1.0f : 0.0f;   // rows 192..199 valid only
    short8 afr[2];
#pragma unroll
    for (int kh = 0; kh < 2; ++kh) {
      const i32x4 up = __builtin_bit_cast(i32x4, u[3][kh]);
      const f32x2* rp = reinterpret_cast<const f32x2*>(
          s_r5 + ir[3] * 68 + kh * 32 + quad * 8);
      i32x4 hpk;
#pragma unroll
      for (int j = 0; j < 4; ++j) {
        const unsigned p = (unsigned)up[j];
        f32x2 uf = {__builtin_bit_cast(float, p << 16),
                    __builtin_bit_cast(float, p & 0xffff0000u)};
        f32x2 s = uf + rp[j];
        hpk[j] = (int)pk2bf(fmaxf(s.x, 0.f), fmaxf(s.y, 0.f));
      }
      afr[kh] = __builtin_bit_cast(short8, hpk);
    }

    f32x4 d[4];
#pragma unroll
    for (int nt = 0; nt < 4; ++nt) {
      f32x4 z = {0.f, 0.f, 0.f, 0.f};
      z = __builtin_amdgcn_mfma_f32_16x16x32_bf16(afr[0], bfr[0][nt], z, 0, 0, 0);
      z = __builtin_amdgcn_mfma_f32_16x16x32_bf16(afr[1], bfr[1][nt], z, 0, 0, 0);
      d[nt] = z;
    }

#pragma unroll
    for (int nt = 0; nt < 4; ++nt) {
      f32x2 p0 = f32x2{d[nt][0], d[nt][1]} + bias2[nt];
      f32x2 p1 = f32x2{d[nt][2], d[nt][3]} + bias2[nt];
      p0.x = fmaxf(p0.x, 0.f); p0.y = fmaxf(p0.y, 0.f);
      p1.x = fmaxf(p1.x, 0.f); p1.y = fmaxf(p1.y, 0.f);
      const f32x2 s = p0 + p1;
      acc2[nt].x += s.x * m;
      acc2[nt].y += s.y * m;
    }
  }

  // collapse pairs, then sum across the 4 quads
  float acc[4];
#pragma unroll
  for (int nt = 0; nt < 4; ++nt) {
    float v = acc2[nt].x + acc2[nt].y;
    v += __shfl_xor(v, 16, 64);
    v += __shfl_xor(v, 32, 64);
    acc[nt] = v;
  }

  if (lane < 16) {
#pragma unroll
    for (int nt = 0; nt < 4; ++nt) red[wave][nt * 16 + lane] = acc[nt];
  }
  __syncthreads();
  if (tid < 64) {
    const float s = red[0][tid] + red[1][tid] + red[2][tid] + red[3][tid];
    out[b * 64 + tid] = s * (1.0f / (float)LL);
  }
}

// ---------------------------------------------------------------------------
// Fallback (no workspace): all-fp32, one block per b, weights in padded LDS.
// ---------------------------------------------------------------------------
__global__ __launch_bounds__(256) void k_fallback(
    const float* __restrict__ v2e, const float* __restrict__ r2e,
    const float* __restrict__ w1W, const float* __restrict__ w1b,
    const float* __restrict__ w2W, const float* __restrict__ w2b,
    const int* __restrict__ huv, const int* __restrict__ hrr,
    float* __restrict__ out)
{
  __shared__ float sw1[64][129];
  __shared__ float sw2[64][65];
  __shared__ float sx[4][128];
  __shared__ float sh[4][64];
  __shared__ float red[4][64];

  const int tid = threadIdx.x;
  const int wave = tid >> 6, lane = tid & 63;
  const int b = blockIdx.x;

  for (int idx = tid; idx < 64 * 128; idx += 256) sw1[idx >> 7][idx & 127] = w1W[idx];
  for (int idx = tid; idx < 64 * 64; idx += 256) sw2[idx >> 6][idx & 63] = w2W[idx];
  __syncthreads();

  const float b1o = w1b[lane], b2o = w2b[lane];
  float acc = 0.f;

  for (int l = wave; l < LL; l += 4) {
    const int iv = huv[b * LL + l];
    const int ir = hrr[b * LL + l];
    sx[wave][lane]      = v2e[iv * 64 + lane];
    sx[wave][64 + lane] = r2e[ir * 64 + lane];
    __syncthreads();
    float h = b1o;
    for (int i = 0; i < 128; ++i) h += sx[wave][i] * sw1[lane][i];
    sh[wave][lane] = fmaxf(h, 0.f);
    __syncthreads();
    float o = b2o;
    for (int i = 0; i < 64; ++i) o += sh[wave][i] * sw2[lane][i];
    acc += fmaxf(o, 0.f);
  }

  red[wave][lane] = acc;
  __syncthreads();
  if (tid < 64) {
    const float s = red[0][tid] + red[1][tid] + red[2][tid] + red[3][tid];
    out[b * 64 + tid] = s * (1.0f / (float)LL);
  }
}

extern "C" void kernel_launch(void* const* d_in, const int* in_sizes, int n_in,
                              void* d_out, int out_size, void* d_ws, size_t ws_size,
                              hipStream_t stream) {
  (void)in_sizes; (void)n_in; (void)out_size;
  const float* v2e = (const float*)d_in[0];   // [100000,64]
  const float* r2e = (const float*)d_in[1];   // [5,64]
  const float* w1W = (const float*)d_in[2];   // [64,128]
  const float* w1b = (const float*)d_in[3];   // [64]
  const float* w2W = (const float*)d_in[4];   // [64,64]
  const float* w2b = (const float*)d_in[5];   // [64]
  // d_in[6] = nodes (unused by uv=True branch)
  const int* huv = (const int*)d_in[7];       // [4096,200]
  const int* hrr = (const int*)d_in[8];       // [4096,200]
  float* out = (float*)d_out;                 // [4096,64]

  const size_t OFF_R5 = (size_t)NITEMS * 64 * sizeof(short);   // 12,800,000
  const size_t OFF_W2 = OFF_R5 + NRATE * 64 * sizeof(float);   // +1,280
  const size_t NEED   = OFF_W2 + 64 * 64 * sizeof(short);      // +8,192

  if (ws_size >= NEED) {
    short* pre_uv = (short*)d_ws;
    float* r5p    = (float*)((char*)d_ws + OFF_R5);
    short* w2p    = (short*)((char*)d_ws + OFF_W2);

    k_pre<<<NBUV + 1, 256, 0, stream>>>(v2e, r2e, w1W, w1b, w2W, pre_uv, w2p, r5p);
    k_main<<<BB, 256, 0, stream>>>(pre_uv, r5p, w2p, w2b, huv, hrr, out);
  } else {
    k_fallback<<<BB, 256, 0, stream>>>(v2e, r2e, w1W, w1b, w2W, w2b, huv, hrr, out);
  }
}

// Round 5
// 115.743 us; speedup vs baseline: 1.1621x; 1.1621x over previous
//
#include <hip/hip_runtime.h>

// Problem constants (from reference)
#define NITEMS 100000
#define NRATE  5
#define BB     4096
#define LL     200
#define DD     64
#define NBUV   391   // pre_uv blocks (391*256 = 100096 >= NITEMS)

typedef short short8  __attribute__((ext_vector_type(8)));
typedef float f32x4   __attribute__((ext_vector_type(4)));
typedef float f32x2   __attribute__((ext_vector_type(2)));
typedef int   i32x4   __attribute__((ext_vector_type(4)));
typedef int   i32x2   __attribute__((ext_vector_type(2)));

// RTNA (round-half-away) fp32->bf16: bits+0x8000, take top 16. Max err 0.5 ulp
// (same as RTNE; only exact-tie behavior differs).
static __device__ __forceinline__ short f2bf(float f) {
  return (short)((__builtin_bit_cast(unsigned, f) + 0x8000u) >> 16);
}
// pack two fp32 -> dword {lo=bf16(a), hi=bf16(b)} : 2 adds + 1 v_perm_b32
static __device__ __forceinline__ unsigned pk2bf(float a, float b) {
  const unsigned ua = __builtin_bit_cast(unsigned, a) + 0x8000u;
  const unsigned ub = __builtin_bit_cast(unsigned, b) + 0x8000u;
  return __builtin_amdgcn_perm(ub, ua, 0x07060302u);
}
// k-space permutation: storage position p holds h-component pi(p)=(p&3)*16+(p>>2).
// Applied consistently to pre_uv, r5p, w2p rows -> all MFMA dots unchanged.
static __device__ __forceinline__ int kperm(int p) {
  return ((p & 3) << 4) | (p >> 2);
}

// ---------------------------------------------------------------------------
// k_pre (R3 structure): blocks 0..NBUV-1: 256 items/block, 64/wave, pipelined.
//   pre_uv[item][p] = bf16(v2e[item] . w1a_row[pi(p)])
// block NBUV: w2p[o*64+p] = bf16(w2W[o][pi(p)]);
//             r5p[r*64+p] = w1b[pi(p)] + r2e[r] . w1b_row[pi(p)]   (fp32)
// ---------------------------------------------------------------------------
__global__ __launch_bounds__(256) void k_pre(
    const float* __restrict__ v2e, const float* __restrict__ r2e,
    const float* __restrict__ w1W, const float* __restrict__ w1b,
    const float* __restrict__ w2W,
    short* __restrict__ pre_uv, short* __restrict__ w2p,
    float* __restrict__ r5p)
{
  const int tid = threadIdx.x;
  const int blk = blockIdx.x;

  if (blk >= NBUV) {
    for (int idx = tid; idx < 64 * 64; idx += 256) {
      const int o = idx >> 6, p = idx & 63;
      w2p[idx] = f2bf(w2W[o * 64 + kperm(p)]);
    }
    for (int idx = tid; idx < NRATE * 64; idx += 256) {
      const int r = idx >> 6, p = idx & 63;
      const int o = kperm(p);
      const float4* wr = reinterpret_cast<const float4*>(w1W + o * 128 + 64);
      const float4* rr = reinterpret_cast<const float4*>(r2e + r * 64);
      float s = w1b[o];
#pragma unroll
      for (int q = 0; q < 16; ++q) {
        const float4 a = wr[q], b = rr[q];
        s += a.x * b.x + a.y * b.y + a.z * b.z + a.w * b.w;
      }
      r5p[r * 64 + p] = s;
    }
    return;
  }

  const int wave = tid >> 6, lane = tid & 63;
  const int n = lane & 15, quad = lane >> 4;

  // B fragment (amortized over 4 MFMA passes): B[k][o], k=kh*32+quad*8+j
  short8 bfr[2][4];
#pragma unroll
  for (int nt = 0; nt < 4; ++nt)
#pragma unroll
    for (int kh = 0; kh < 2; ++kh) {
      const float4* p = reinterpret_cast<const float4*>(
          w1W + (nt * 16 + n) * 128 + kh * 32 + quad * 8);
      const float4 x0 = p[0], x1 = p[1];
      i32x4 pk = {(int)pk2bf(x0.x, x0.y), (int)pk2bf(x0.z, x0.w),
                  (int)pk2bf(x1.x, x1.y), (int)pk2bf(x1.z, x1.w)};
      bfr[kh][nt] = __builtin_bit_cast(short8, pk);
    }

  const int ibase_w = blk * 256 + wave * 64;

  // software-pipelined A loads: A[m=n][k=kh*32+quad*8+j]
  float4 cur0, cur1, cur2, cur3;
  {
    const int row = min(ibase_w + n, NITEMS - 1);
    const float4* p = reinterpret_cast<const float4*>(v2e + (size_t)row * 64 + quad * 8);
    cur0 = p[0]; cur1 = p[1];
    const float4* q = reinterpret_cast<const float4*>(v2e + (size_t)row * 64 + 32 + quad * 8);
    cur2 = q[0]; cur3 = q[1];
  }

#pragma unroll
  for (int it = 0; it < 4; ++it) {
    float4 nx0, nx1, nx2, nx3;
    if (it < 3) {
      const int row = min(ibase_w + (it + 1) * 16 + n, NITEMS - 1);
      const float4* p = reinterpret_cast<const float4*>(v2e + (size_t)row * 64 + quad * 8);
      nx0 = p[0]; nx1 = p[1];
      const float4* q = reinterpret_cast<const float4*>(v2e + (size_t)row * 64 + 32 + quad * 8);
      nx2 = q[0]; nx3 = q[1];
    }

    short8 afr[2];
    {
      i32x4 pk0 = {(int)pk2bf(cur0.x, cur0.y), (int)pk2bf(cur0.z, cur0.w),
                   (int)pk2bf(cur1.x, cur1.y), (int)pk2bf(cur1.z, cur1.w)};
      afr[0] = __builtin_bit_cast(short8, pk0);
      i32x4 pk1 = {(int)pk2bf(cur2.x, cur2.y), (int)pk2bf(cur2.z, cur2.w),
                   (int)pk2bf(cur3.x, cur3.y), (int)pk2bf(cur3.z, cur3.w)};
      afr[1] = __builtin_bit_cast(short8, pk1);
    }

    f32x4 d[4];
#pragma unroll
    for (int nt = 0; nt < 4; ++nt) {
      f32x4 z = {0.f, 0.f, 0.f, 0.f};
      z = __builtin_amdgcn_mfma_f32_16x16x32_bf16(afr[0], bfr[0][nt], z, 0, 0, 0);
      z = __builtin_amdgcn_mfma_f32_16x16x32_bf16(afr[1], bfr[1][nt], z, 0, 0, 0);
      d[nt] = z;
    }

    // C/D: lane (n,quad), reg (nt,r) = row quad*4+r, col nt*16+n.
    // kperm store: cols {nt*16+n} -> positions n*4+nt, one 8B store per r.
#pragma unroll
    for (int r = 0; r < 4; ++r) {
      const int item = ibase_w + it * 16 + quad * 4 + r;
      if (item < NITEMS) {
        i32x2 s = {(int)pk2bf(d[0][r], d[1][r]), (int)pk2bf(d[2][r], d[3][r])};
        *reinterpret_cast<i32x2*>(pre_uv + (size_t)item * 64 + n * 4) = s;
      }
    }

    if (it < 3) { cur0 = nx0; cur1 = nx1; cur2 = nx2; cur3 = nx3; }
  }
}

// ---------------------------------------------------------------------------
// k_main: wave-per-b (1024 blocks x 4 waves). Each wave owns one b and its
// 13 l-tiles; ALL 26 pre_uv gathers issued before any compute (max MLP —
// the kernel is gather-latency-bound). r5 table in LDS (one barrier).
// Tiles 0..11 unmasked; tile 12 = 8-row tail via 0/1 multiplier.
// ---------------------------------------------------------------------------
__global__ __launch_bounds__(256) void k_main(
    const short* __restrict__ pre_uv, const float* __restrict__ r5p,
    const short* __restrict__ w2p, const float* __restrict__ w2b,
    const int* __restrict__ huv, const int* __restrict__ hrr,
    float* __restrict__ out)
{
  __shared__ __align__(16) float s_r5[5 * 68];   // stride 68 spreads row starts

  const int tid  = threadIdx.x;
  const int wave = tid >> 6, lane = tid & 63;
  const int n = lane & 15, quad = lane >> 4;
  const int b = blockIdx.x * 4 + wave;

  for (int idx = tid; idx < 5 * 64; idx += 256)
    s_r5[(idx >> 6) * 68 + (idx & 63)] = r5p[idx];

  const int* hu = huv + b * LL;
  const int* hr = hrr + b * LL;

  // tile t covers rows l = t*16 + m (m = A-row = n). Tail tile 12: l=192..199.
  int iv[13], ir[13];
#pragma unroll
  for (int t = 0; t < 12; ++t) {
    iv[t] = hu[t * 16 + n];
    ir[t] = hr[t * 16 + n];
  }
  {
    const int lc = min(192 + n, LL - 1);
    iv[12] = hu[lc];
    ir[12] = hr[lc];
  }

  // issue ALL pre_uv gathers (26 independent 16B loads in flight per wave)
  short8 u[13][2];
#pragma unroll
  for (int t = 0; t < 13; ++t)
#pragma unroll
    for (int kh = 0; kh < 2; ++kh)
      u[t][kh] = *reinterpret_cast<const short8*>(
          pre_uv + (size_t)iv[t] * 64 + kh * 32 + quad * 8);

  // B fragments for W2 (permuted k-space): B[p][o] = w2p[o*64+p]
  short8 bfr[2][4];
#pragma unroll
  for (int nt = 0; nt < 4; ++nt)
#pragma unroll
    for (int kh = 0; kh < 2; ++kh)
      bfr[kh][nt] = *reinterpret_cast<const short8*>(
          w2p + (nt * 16 + n) * 64 + kh * 32 + quad * 8);

  f32x2 bias2[4];
#pragma unroll
  for (int nt = 0; nt < 4; ++nt) {
    const float bv = w2b[nt * 16 + n];
    bias2[nt] = f32x2{bv, bv};
  }

  __syncthreads();  // s_r5 ready

  const float tailm = (quad < 2) ? 1.0f : 0.0f;  // tile-12 valid rows: m<8
  f32x2 acc2[4] = {{0.f, 0.f}, {0.f, 0.f}, {0.f, 0.f}, {0.f, 0.f}};

#pragma unroll
  for (int t = 0; t < 13; ++t) {
    short8 afr[2];
#pragma unroll
    for (int kh = 0; kh < 2; ++kh) {
      const i32x4 up = __builtin_bit_cast(i32x4, u[t][kh]);
      const f32x2* rp = reinterpret_cast<const f32x2*>(
          s_r5 + ir[t] * 68 + kh * 32 + quad * 8);
      i32x4 hpk;
#pragma unroll
      for (int j = 0; j < 4; ++j) {
        const unsigned p = (unsigned)up[j];
        f32x2 uf = {__builtin_bit_cast(float, p << 16),
                    __builtin_bit_cast(float, p & 0xffff0000u)};
        const f32x2 s = uf + rp[j];
        hpk[j] = (int)pk2bf(fmaxf(s.x, 0.f), fmaxf(s.y, 0.f));
      }
      afr[kh] = __builtin_bit_cast(short8, hpk);
    }

    f32x4 d[4];
#pragma unroll
    for (int nt = 0; nt < 4; ++nt) {
      f32x4 z = {0.f, 0.f, 0.f, 0.f};
      z = __builtin_amdgcn_mfma_f32_16x16x32_bf16(afr[0], bfr[0][nt], z, 0, 0, 0);
      z = __builtin_amdgcn_mfma_f32_16x16x32_bf16(afr[1], bfr[1][nt], z, 0, 0, 0);
      d[nt] = z;
    }

#pragma unroll
    for (int nt = 0; nt < 4; ++nt) {
      f32x2 p0 = f32x2{d[nt][0], d[nt][1]} + bias2[nt];
      f32x2 p1 = f32x2{d[nt][2], d[nt][3]} + bias2[nt];
      p0.x = fmaxf(p0.x, 0.f); p0.y = fmaxf(p0.y, 0.f);
      p1.x = fmaxf(p1.x, 0.f); p1.y = fmaxf(p1.y, 0.f);
      f32x2 s = p0 + p1;
      if (t == 12) { s.x *= tailm; s.y *= tailm; }
      acc2[nt] += s;
    }
  }

  // collapse pairs, sum across the 4 quads -> every lane has all 4 sums
  float acc[4];
#pragma unroll
  for (int nt = 0; nt < 4; ++nt) {
    float v = acc2[nt].x + acc2[nt].y;
    v += __shfl_xor(v, 16, 64);
    v += __shfl_xor(v, 32, 64);
    acc[nt] = v;
  }

  // coalesced: lane (n,quad) stores column quad*16+n (one dword per lane)
  out[b * 64 + quad * 16 + n] = acc[quad] * (1.0f / (float)LL);
}

// ---------------------------------------------------------------------------
// Fallback (no workspace): all-fp32, one block per b, weights in padded LDS.
// ---------------------------------------------------------------------------
__global__ __launch_bounds__(256) void k_fallback(
    const float* __restrict__ v2e, const float* __restrict__ r2e,
    const float* __restrict__ w1W, const float* __restrict__ w1b,
    const float* __restrict__ w2W, const float* __restrict__ w2b,
    const int* __restrict__ huv, const int* __restrict__ hrr,
    float* __restrict__ out)
{
  __shared__ float sw1[64][129];
  __shared__ float sw2[64][65];
  __shared__ float sx[4][128];
  __shared__ float sh[4][64];
  __shared__ float red[4][64];

  const int tid = threadIdx.x;
  const int wave = tid >> 6, lane = tid & 63;
  const int b = blockIdx.x;

  for (int idx = tid; idx < 64 * 128; idx += 256) sw1[idx >> 7][idx & 127] = w1W[idx];
  for (int idx = tid; idx < 64 * 64; idx += 256) sw2[idx >> 6][idx & 63] = w2W[idx];
  __syncthreads();

  const float b1o = w1b[lane], b2o = w2b[lane];
  float acc = 0.f;

  for (int l = wave; l < LL; l += 4) {
    const int iv = huv[b * LL + l];
    const int ir = hrr[b * LL + l];
    sx[wave][lane]      = v2e[iv * 64 + lane];
    sx[wave][64 + lane] = r2e[ir * 64 + lane];
    __syncthreads();
    float h = b1o;
    for (int i = 0; i < 128; ++i) h += sx[wave][i] * sw1[lane][i];
    sh[wave][lane] = fmaxf(h, 0.f);
    __syncthreads();
    float o = b2o;
    for (int i = 0; i < 64; ++i) o += sh[wave][i] * sw2[lane][i];
    acc += fmaxf(o, 0.f);
  }

  red[wave][lane] = acc;
  __syncthreads();
  if (tid < 64) {
    const float s = red[0][tid] + red[1][tid] + red[2][tid] + red[3][tid];
    out[b * 64 + tid] = s * (1.0f / (float)LL);
  }
}

extern "C" void kernel_launch(void* const* d_in, const int* in_sizes, int n_in,
                              void* d_out, int out_size, void* d_ws, size_t ws_size,
                              hipStream_t stream) {
  (void)in_sizes; (void)n_in; (void)out_size;
  const float* v2e = (const float*)d_in[0];   // [100000,64]
  const float* r2e = (const float*)d_in[1];   // [5,64]
  const float* w1W = (const float*)d_in[2];   // [64,128]
  const float* w1b = (const float*)d_in[3];   // [64]
  const float* w2W = (const float*)d_in[4];   // [64,64]
  const float* w2b = (const float*)d_in[5];   // [64]
  // d_in[6] = nodes (unused by uv=True branch)
  const int* huv = (const int*)d_in[7];       // [4096,200]
  const int* hrr = (const int*)d_in[8];       // [4096,200]
  float* out = (float*)d_out;                 // [4096,64]

  const size_t OFF_R5 = (size_t)NITEMS * 64 * sizeof(short);   // 12,800,000
  const size_t OFF_W2 = OFF_R5 + NRATE * 64 * sizeof(float);   // +1,280
  const size_t NEED   = OFF_W2 + 64 * 64 * sizeof(short);      // +8,192

  if (ws_size >= NEED) {
    short* pre_uv = (short*)d_ws;
    float* r5p    = (float*)((char*)d_ws + OFF_R5);
    short* w2p    = (short*)((char*)d_ws + OFF_W2);

    k_pre<<<NBUV + 1, 256, 0, stream>>>(v2e, r2e, w1W, w1b, w2W, pre_uv, w2p, r5p);
    k_main<<<BB / 4, 256, 0, stream>>>(pre_uv, r5p, w2p, w2b, huv, hrr, out);
  } else {
    k_fallback<<<BB, 256, 0, stream>>>(v2e, r2e, w1W, w1b, w2W, w2b, huv, hrr, out);
  }
}